// Round 6
// baseline (1598.838 us; speedup 1.0000x reference)
//
#include <hip/hip_runtime.h>

#ifndef __HIP_PLATFORM_AMD__
#define unsafeAtomicAdd atomicAdd
#endif

// ---------------------------------------------------------------------------
// GCN, 6 layers, N=1M nodes, E=16M edges.
// R6: latency-bound fix. Edges ordered by (dst_bucket[4096], src_superblock
// [256K]) as in R5. Each bucket's edges are split across 2 blocks (grid 490
// => 2 blocks/CU = 32 waves, was 1 block = 16) and the gather loop is
// unrolled 8-wide (8 independent gathers in flight, was 4). Each block
// accumulates into LDS then flushes densely (coalesced unsafeAtomicAdd) into
// global agg planes; a light node kernel applies norm/GEMV/ReLU and re-zeros
// the planes. Layer 6 applies W6 before aggregation.
// ---------------------------------------------------------------------------

#define BT 256            // small-kernel block size
#define NBLK 256          // partition blocks
#define BSHIFT 12         // 4096 nodes per dst bucket
#define BSIZE 4096
#define LMASK 4095
#define SSH 18            // src super-block shift
#define NBINS 1024        // (dst_bucket<<2)|src_sb
#define M (NBLK * NBINS)  // 262144
#define BTL 1024          // edge-kernel block size

__device__ __forceinline__ int edge_key(int s, int d) {
  return ((d >> BSHIFT) << 2) | (s >> SSH);
}

// s0 = feat * norm
__global__ void k_init(const float* __restrict__ feat, const float* __restrict__ norm,
                       float* __restrict__ s0, int N) {
  int i = blockIdx.x * BT + threadIdx.x;
  if (i < N) s0[i] = feat[i] * norm[i];
}

// zero the 3 agg planes (ws is poisoned 0xAA before every timed launch)
__global__ void k_zero3(float* __restrict__ a0, float* __restrict__ a1,
                        float* __restrict__ a2, int N) {
  int i = blockIdx.x * BT + threadIdx.x;
  if (i < N) { a0[i] = 0.0f; a1[i] = 0.0f; a2[i] = 0.0f; }
}

// P1: per-block LDS histogram of (dst_bucket, src_sb) bins
__global__ void k_phist(const int* __restrict__ src, const int* __restrict__ dst,
                        int* __restrict__ histB, int E, int chunk) {
  __shared__ int h[NBINS];
  for (int i = threadIdx.x; i < NBINS; i += BT) h[i] = 0;
  __syncthreads();
  int b = blockIdx.x;
  int beg = b * chunk, end = min(beg + chunk, E);
  int i = beg + (int)threadIdx.x * 4;  // beg is 16B-aligned (chunk % 4 == 0)
  for (; i + 3 < end; i += BT * 4) {
    int4 u = *(const int4*)(src + i);
    int4 v = *(const int4*)(dst + i);
    atomicAdd(&h[edge_key(u.x, v.x)], 1);
    atomicAdd(&h[edge_key(u.y, v.y)], 1);
    atomicAdd(&h[edge_key(u.z, v.z)], 1);
    atomicAdd(&h[edge_key(u.w, v.w)], 1);
  }
  for (; i < end; ++i) atomicAdd(&h[edge_key(src[i], dst[i])], 1);
  __syncthreads();
  for (int k = threadIdx.x; k < NBINS; k += BT) histB[b * NBINS + k] = h[k];
}

// Tiled transpose: in[R][C] -> out[C][R]. R,C multiples of 64. grid(C/64,R/64)
__global__ void k_transp(const int* __restrict__ in, int* __restrict__ out, int R, int C) {
  __shared__ int tile[64][65];
  int c0 = blockIdx.x * 64, r0 = blockIdx.y * 64;
  int tx = threadIdx.x & 63, ty = threadIdx.x >> 6;  // 64 x 4
  for (int j = 0; j < 16; ++j) {
    int r = ty + j * 4;
    tile[r][tx] = in[(r0 + r) * C + c0 + tx];
  }
  __syncthreads();
  for (int j = 0; j < 16; ++j) {
    int r = ty + j * 4;
    out[(c0 + r) * R + r0 + tx] = tile[tx][r];
  }
}

// scan A: per-block sums
__global__ void k_blockSum(const int* __restrict__ data, int* __restrict__ partial, int Mlen) {
  __shared__ int tmp[BT];
  int i = blockIdx.x * BT + threadIdx.x;
  tmp[threadIdx.x] = (i < Mlen) ? data[i] : 0;
  __syncthreads();
  for (int off = BT / 2; off > 0; off >>= 1) {
    if (threadIdx.x < off) tmp[threadIdx.x] += tmp[threadIdx.x + off];
    __syncthreads();
  }
  if (threadIdx.x == 0) partial[blockIdx.x] = tmp[0];
}

// scan B: exclusive scan of partials in place (single block)
__global__ void k_scanPartials(int* __restrict__ partial, int nb) {
  __shared__ int tmp[BT];
  __shared__ int carry;
  int t = threadIdx.x;
  if (t == 0) carry = 0;
  __syncthreads();
  for (int base = 0; base < nb; base += BT) {
    int i = base + t;
    int v = (i < nb) ? partial[i] : 0;
    tmp[t] = v;
    __syncthreads();
    for (int off = 1; off < BT; off <<= 1) {
      int x = 0;
      if (t >= off) x = tmp[t - off];
      __syncthreads();
      tmp[t] += x;
      __syncthreads();
    }
    if (i < nb) partial[i] = tmp[t] - v + carry;
    __syncthreads();
    if (t == BT - 1) carry += tmp[BT - 1];
    __syncthreads();
  }
}

// scan C: final exclusive scan in place
__global__ void k_scanFinal(int* __restrict__ data, const int* __restrict__ partial, int Mlen) {
  __shared__ int tmp[BT];
  int t = threadIdx.x;
  int i = blockIdx.x * BT + t;
  int v = (i < Mlen) ? data[i] : 0;
  tmp[t] = v;
  __syncthreads();
  for (int off = 1; off < BT; off <<= 1) {
    int x = 0;
    if (t >= off) x = tmp[t - off];
    __syncthreads();
    tmp[t] += x;
    __syncthreads();
  }
  if (i < Mlen) data[i] = tmp[t] - v + partial[blockIdx.x];
}

// P2: scatter packed edges with per-block LDS cursors
__global__ void k_pscatter(const int* __restrict__ src, const int* __restrict__ dst,
                           const int* __restrict__ scanT, unsigned int* __restrict__ packed,
                           int E, int chunk) {
  __shared__ int cur[NBINS];
  int b = blockIdx.x;
  for (int k = threadIdx.x; k < NBINS; k += BT) cur[k] = scanT[b * NBINS + k];
  __syncthreads();
  int beg = b * chunk, end = min(beg + chunk, E);
  int i = beg + (int)threadIdx.x * 4;
  for (; i + 3 < end; i += BT * 4) {
    int4 u = *(const int4*)(src + i);
    int4 v = *(const int4*)(dst + i);
    int p;
    p = atomicAdd(&cur[edge_key(u.x, v.x)], 1);
    packed[p] = ((unsigned)u.x << BSHIFT) | (unsigned)(v.x & LMASK);
    p = atomicAdd(&cur[edge_key(u.y, v.y)], 1);
    packed[p] = ((unsigned)u.y << BSHIFT) | (unsigned)(v.y & LMASK);
    p = atomicAdd(&cur[edge_key(u.z, v.z)], 1);
    packed[p] = ((unsigned)u.z << BSHIFT) | (unsigned)(v.z & LMASK);
    p = atomicAdd(&cur[edge_key(u.w, v.w)], 1);
    packed[p] = ((unsigned)u.w << BSHIFT) | (unsigned)(v.w & LMASK);
  }
  for (; i < end; ++i) {
    int p = atomicAdd(&cur[edge_key(src[i], dst[i])], 1);
    packed[p] = ((unsigned)src[i] << BSHIFT) | (unsigned)(dst[i] & LMASK);
  }
}

// --- edge kernels: 2 blocks per dst bucket, LDS accumulate, dense flush ---

#define ACC3(p)                                             \
  {                                                         \
    unsigned pp = (p);                                      \
    float4 m = ((const float4*)sPrev)[pp >> BSHIFT];        \
    int loc = pp & LMASK;                                   \
    atomicAdd(&a0[loc], m.x);                               \
    atomicAdd(&a1[loc], m.y);                               \
    atomicAdd(&a2[loc], m.z);                               \
  }

#define ACC1(p)                                             \
  {                                                         \
    unsigned pp = (p);                                      \
    atomicAdd(&a[pp & LMASK], sIn[pp >> BSHIFT]);           \
  }

// 3-feature edge pass (layers 2-5)
__global__ __launch_bounds__(BTL) void k_edge3p(
    const int* __restrict__ scanT, const unsigned int* __restrict__ packed,
    const float* __restrict__ sPrev, float* __restrict__ agg0,
    float* __restrict__ agg1, float* __restrict__ agg2, int N) {
  __shared__ float a0[BSIZE], a1[BSIZE], a2[BSIZE];
  int k = blockIdx.x >> 1, h = blockIdx.x & 1;
  for (int i = threadIdx.x; i < BSIZE; i += BTL) { a0[i] = 0.0f; a1[i] = 0.0f; a2[i] = 0.0f; }
  int bbeg = scanT[k << 2], bend = scanT[(k << 2) + 4];
  int mid = bbeg + ((bend - bbeg) >> 1);
  int beg = h ? mid : bbeg;
  int end = h ? bend : mid;
  __syncthreads();
  int abeg = min(end, (beg + 3) & ~3);
  {
    int t = beg + (int)threadIdx.x;
    if (t < abeg) ACC3(packed[t]);
  }
  int i = abeg + (int)threadIdx.x * 8;
  for (; i + 7 < end; i += BTL * 8) {
    uint4 pa = *(const uint4*)(packed + i);
    uint4 pb = *(const uint4*)(packed + i + 4);
    float4 m0 = ((const float4*)sPrev)[pa.x >> BSHIFT];
    float4 m1 = ((const float4*)sPrev)[pa.y >> BSHIFT];
    float4 m2 = ((const float4*)sPrev)[pa.z >> BSHIFT];
    float4 m3 = ((const float4*)sPrev)[pa.w >> BSHIFT];
    float4 m4 = ((const float4*)sPrev)[pb.x >> BSHIFT];
    float4 m5 = ((const float4*)sPrev)[pb.y >> BSHIFT];
    float4 m6 = ((const float4*)sPrev)[pb.z >> BSHIFT];
    float4 m7 = ((const float4*)sPrev)[pb.w >> BSHIFT];
    atomicAdd(&a0[pa.x & LMASK], m0.x); atomicAdd(&a1[pa.x & LMASK], m0.y); atomicAdd(&a2[pa.x & LMASK], m0.z);
    atomicAdd(&a0[pa.y & LMASK], m1.x); atomicAdd(&a1[pa.y & LMASK], m1.y); atomicAdd(&a2[pa.y & LMASK], m1.z);
    atomicAdd(&a0[pa.z & LMASK], m2.x); atomicAdd(&a1[pa.z & LMASK], m2.y); atomicAdd(&a2[pa.z & LMASK], m2.z);
    atomicAdd(&a0[pa.w & LMASK], m3.x); atomicAdd(&a1[pa.w & LMASK], m3.y); atomicAdd(&a2[pa.w & LMASK], m3.z);
    atomicAdd(&a0[pb.x & LMASK], m4.x); atomicAdd(&a1[pb.x & LMASK], m4.y); atomicAdd(&a2[pb.x & LMASK], m4.z);
    atomicAdd(&a0[pb.y & LMASK], m5.x); atomicAdd(&a1[pb.y & LMASK], m5.y); atomicAdd(&a2[pb.y & LMASK], m5.z);
    atomicAdd(&a0[pb.z & LMASK], m6.x); atomicAdd(&a1[pb.z & LMASK], m6.y); atomicAdd(&a2[pb.z & LMASK], m6.z);
    atomicAdd(&a0[pb.w & LMASK], m7.x); atomicAdd(&a1[pb.w & LMASK], m7.y); atomicAdd(&a2[pb.w & LMASK], m7.z);
  }
  for (; i < end; ++i) ACC3(packed[i]);
  __syncthreads();
  int node0 = k << BSHIFT;
  for (int t = threadIdx.x; t < BSIZE; t += BTL) {
    int node = node0 + t;
    if (node < N) {
      unsafeAtomicAdd(&agg0[node], a0[t]);
      unsafeAtomicAdd(&agg1[node], a1[t]);
      unsafeAtomicAdd(&agg2[node], a2[t]);
    }
  }
}

// scalar edge pass (layers 1 and 6)
__global__ __launch_bounds__(BTL) void k_edge1p(
    const int* __restrict__ scanT, const unsigned int* __restrict__ packed,
    const float* __restrict__ sIn, float* __restrict__ agg0, int N) {
  __shared__ float a[BSIZE];
  int k = blockIdx.x >> 1, h = blockIdx.x & 1;
  for (int i = threadIdx.x; i < BSIZE; i += BTL) a[i] = 0.0f;
  int bbeg = scanT[k << 2], bend = scanT[(k << 2) + 4];
  int mid = bbeg + ((bend - bbeg) >> 1);
  int beg = h ? mid : bbeg;
  int end = h ? bend : mid;
  __syncthreads();
  int abeg = min(end, (beg + 3) & ~3);
  {
    int t = beg + (int)threadIdx.x;
    if (t < abeg) ACC1(packed[t]);
  }
  int i = abeg + (int)threadIdx.x * 8;
  for (; i + 7 < end; i += BTL * 8) {
    uint4 pa = *(const uint4*)(packed + i);
    uint4 pb = *(const uint4*)(packed + i + 4);
    float m0 = sIn[pa.x >> BSHIFT];
    float m1 = sIn[pa.y >> BSHIFT];
    float m2 = sIn[pa.z >> BSHIFT];
    float m3 = sIn[pa.w >> BSHIFT];
    float m4 = sIn[pb.x >> BSHIFT];
    float m5 = sIn[pb.y >> BSHIFT];
    float m6 = sIn[pb.z >> BSHIFT];
    float m7 = sIn[pb.w >> BSHIFT];
    atomicAdd(&a[pa.x & LMASK], m0);
    atomicAdd(&a[pa.y & LMASK], m1);
    atomicAdd(&a[pa.z & LMASK], m2);
    atomicAdd(&a[pa.w & LMASK], m3);
    atomicAdd(&a[pb.x & LMASK], m4);
    atomicAdd(&a[pb.y & LMASK], m5);
    atomicAdd(&a[pb.z & LMASK], m6);
    atomicAdd(&a[pb.w & LMASK], m7);
  }
  for (; i < end; ++i) ACC1(packed[i]);
  __syncthreads();
  int node0 = k << BSHIFT;
  for (int t = threadIdx.x; t < BSIZE; t += BTL) {
    int node = node0 + t;
    if (node < N) unsafeAtomicAdd(&agg0[node], a[t]);
  }
}

// --- node kernels: combine agg planes, GEMV/ReLU, re-zero planes ---

// Layer 1 (1->3): sA = relu((agg0*n)W1+b1)*n (float4), zero agg0
__global__ void k_node12(const float* __restrict__ norm, const float* __restrict__ W1,
                         const float* __restrict__ b1, float* __restrict__ agg0,
                         float* __restrict__ sA, int N) {
  int i = blockIdx.x * BT + threadIdx.x;
  if (i >= N) return;
  float n = norm[i];
  float pre = agg0[i] * n;
  agg0[i] = 0.0f;
  float h0 = fmaxf(0.0f, pre * W1[0] + b1[0]);
  float h1 = fmaxf(0.0f, pre * W1[1] + b1[1]);
  float h2 = fmaxf(0.0f, pre * W1[2] + b1[2]);
  ((float4*)sA)[i] = make_float4(h0 * n, h1 * n, h2 * n, 0.0f);
}

// Layers 2-4 (3->3)
__global__ void k_node33(const float* __restrict__ norm, const float* __restrict__ W,
                         const float* __restrict__ bias, float* __restrict__ agg0,
                         float* __restrict__ agg1, float* __restrict__ agg2,
                         float* __restrict__ sNext, int N) {
  int i = blockIdx.x * BT + threadIdx.x;
  if (i >= N) return;
  float n = norm[i];
  float x0 = agg0[i] * n, x1 = agg1[i] * n, x2 = agg2[i] * n;
  agg0[i] = 0.0f; agg1[i] = 0.0f; agg2[i] = 0.0f;
  float h0 = fmaxf(0.0f, x0 * W[0] + x1 * W[3] + x2 * W[6] + bias[0]);
  float h1 = fmaxf(0.0f, x0 * W[1] + x1 * W[4] + x2 * W[7] + bias[1]);
  float h2 = fmaxf(0.0f, x0 * W[2] + x1 * W[5] + x2 * W[8] + bias[2]);
  ((float4*)sNext)[i] = make_float4(h0 * n, h1 * n, h2 * n, 0.0f);
}

// Layer 5 + layer-6 pre-transform: sB = (relu((agg*n)W5+b5) @ W6) * n
__global__ void k_node56(const float* __restrict__ norm, const float* __restrict__ W5,
                         const float* __restrict__ b5, const float* __restrict__ W6,
                         float* __restrict__ agg0, float* __restrict__ agg1,
                         float* __restrict__ agg2, float* __restrict__ sB, int N) {
  int i = blockIdx.x * BT + threadIdx.x;
  if (i >= N) return;
  float n = norm[i];
  float x0 = agg0[i] * n, x1 = agg1[i] * n, x2 = agg2[i] * n;
  agg0[i] = 0.0f; agg1[i] = 0.0f; agg2[i] = 0.0f;
  float h0 = fmaxf(0.0f, x0 * W5[0] + x1 * W5[3] + x2 * W5[6] + b5[0]);
  float h1 = fmaxf(0.0f, x0 * W5[1] + x1 * W5[4] + x2 * W5[7] + b5[1]);
  float h2 = fmaxf(0.0f, x0 * W5[2] + x1 * W5[5] + x2 * W5[8] + b5[2]);
  sB[i] = (h0 * W6[0] + h1 * W6[1] + h2 * W6[2]) * n;
}

// out = relu(agg0 * n + b6)
__global__ void k_final(const float* __restrict__ norm, const float* __restrict__ b6,
                        const float* __restrict__ agg0, float* __restrict__ out, int N) {
  int i = blockIdx.x * BT + threadIdx.x;
  if (i >= N) return;
  out[i] = fmaxf(0.0f, agg0[i] * norm[i] + b6[0]);
}

extern "C" void kernel_launch(void* const* d_in, const int* in_sizes, int n_in,
                              void* d_out, int out_size, void* d_ws, size_t ws_size,
                              hipStream_t stream) {
  const float* feat = (const float*)d_in[0];
  const float* norm = (const float*)d_in[1];
  const int* src = (const int*)d_in[2];
  const int* dst = (const int*)d_in[3];
  const float* W1 = (const float*)d_in[4];
  const float* b1 = (const float*)d_in[5];
  const float* W2 = (const float*)d_in[6];
  const float* b2 = (const float*)d_in[7];
  const float* W3 = (const float*)d_in[8];
  const float* b3 = (const float*)d_in[9];
  const float* W4 = (const float*)d_in[10];
  const float* b4 = (const float*)d_in[11];
  const float* W5 = (const float*)d_in[12];
  const float* b5 = (const float*)d_in[13];
  const float* W6 = (const float*)d_in[14];
  const float* b6 = (const float*)d_in[15];
  float* out = (float*)d_out;

  const int N = in_sizes[0];
  const int E = in_sizes[2];
  const int nbNode = (N + BT - 1) / BT;
  const int nBkt = (N + BSIZE - 1) >> BSHIFT;                 // 245
  const int chunk = (((E + NBLK - 1) / NBLK) + 3) & ~3;       // 16B-aligned chunks

  // Workspace: packed[E] | histB[M] | histT[M] | scanT[M] | partial[M/BT] |
  //            s0B[N]f | sA[4N]f | sA2[4N]f | agg0[N]f | agg1[N]f | agg2[N]f  (~115 MB)
  unsigned int* packed = (unsigned int*)d_ws;
  int* histB = (int*)(packed + (size_t)E);
  int* histT = histB + (size_t)M;
  int* scanT = histT + (size_t)M;
  int* partial = scanT + (size_t)M;
  float* s0B = (float*)(partial + M / BT);
  float* sA = s0B + (size_t)N;
  float* sA2 = sA + (size_t)4 * N;
  float* agg0 = sA2 + (size_t)4 * N;
  float* agg1 = agg0 + (size_t)N;
  float* agg2 = agg1 + (size_t)N;

  // --- Build (dst_bucket, src_superblock)-ordered edge list ---
  k_init<<<nbNode, BT, 0, stream>>>(feat, norm, s0B, N);
  k_zero3<<<nbNode, BT, 0, stream>>>(agg0, agg1, agg2, N);
  k_phist<<<NBLK, BT, 0, stream>>>(src, dst, histB, E, chunk);
  {
    dim3 g1(NBINS / 64, NBLK / 64);  // histB[NBLK][NBINS] -> histT[NBINS][NBLK]
    k_transp<<<g1, BT, 0, stream>>>(histB, histT, NBLK, NBINS);
  }
  k_blockSum<<<M / BT, BT, 0, stream>>>(histT, partial, M);
  k_scanPartials<<<1, BT, 0, stream>>>(partial, M / BT);
  k_scanFinal<<<M / BT, BT, 0, stream>>>(histT, partial, M);
  {
    dim3 g2(NBLK / 64, NBINS / 64);  // histT[NBINS][NBLK] (scanned) -> scanT[NBLK][NBINS]
    k_transp<<<g2, BT, 0, stream>>>(histT, scanT, NBINS, NBLK);
  }
  k_pscatter<<<NBLK, BT, 0, stream>>>(src, dst, scanT, packed, E, chunk);

  const int gEdge = nBkt * 2;  // 2 blocks per bucket

  // --- 6 layers ---
  k_edge1p<<<gEdge, BTL, 0, stream>>>(scanT, packed, s0B, agg0, N);
  k_node12<<<nbNode, BT, 0, stream>>>(norm, W1, b1, agg0, sA, N);

  k_edge3p<<<gEdge, BTL, 0, stream>>>(scanT, packed, sA, agg0, agg1, agg2, N);
  k_node33<<<nbNode, BT, 0, stream>>>(norm, W2, b2, agg0, agg1, agg2, sA2, N);

  k_edge3p<<<gEdge, BTL, 0, stream>>>(scanT, packed, sA2, agg0, agg1, agg2, N);
  k_node33<<<nbNode, BT, 0, stream>>>(norm, W3, b3, agg0, agg1, agg2, sA, N);

  k_edge3p<<<gEdge, BTL, 0, stream>>>(scanT, packed, sA, agg0, agg1, agg2, N);
  k_node33<<<nbNode, BT, 0, stream>>>(norm, W4, b4, agg0, agg1, agg2, sA2, N);

  k_edge3p<<<gEdge, BTL, 0, stream>>>(scanT, packed, sA2, agg0, agg1, agg2, N);
  k_node56<<<nbNode, BT, 0, stream>>>(norm, W5, b5, W6, agg0, agg1, agg2, s0B, N);

  k_edge1p<<<gEdge, BTL, 0, stream>>>(scanT, packed, s0B, agg0, N);
  k_final<<<nbNode, BT, 0, stream>>>(norm, b6, agg0, out, N);
}